// Round 17
// baseline (237.300 us; speedup 1.0000x reference)
//
#include <hip/hip_runtime.h>

typedef __bf16 bf16_t;
typedef __bf16 bf16x8 __attribute__((ext_vector_type(8)));
typedef __bf16 bf16x4 __attribute__((ext_vector_type(4)));
typedef float f32x4 __attribute__((ext_vector_type(4)));

static __device__ __forceinline__ f32x4 mfma16(bf16x8 a, bf16x8 b, f32x4 c) {
    return __builtin_amdgcn_mfma_f32_16x16x32_bf16(a, b, c, 0, 0, 0);
}
static __device__ __forceinline__ float exp2v(float x) {
    float r; asm("v_exp_f32 %0, %1" : "=v"(r) : "v"(x)); return r;
}

#define AS1 __attribute__((address_space(1)))
#define AS3 __attribute__((address_space(3)))
static __device__ __forceinline__ void gload16(const void* g, void* l) {
    __builtin_amdgcn_global_load_lds((AS1 const void*)g, (AS3 void*)l, 16, 0, 0);
}

constexpr int B_ = 2, S_ = 2048, H_ = 16, DH = 128, AF = 2048;
constexpr int M_ = B_ * S_;  // 4096

// ---------------- fused prep: query cvt + Wq/Wk/Wv transpose + Wo transpose ----------------
__global__ __launch_bounds__(256) void prep(
    const float* __restrict__ query, const float* __restrict__ Wq,
    const float* __restrict__ Wk, const float* __restrict__ Wv,
    const float* __restrict__ Wo, bf16_t* __restrict__ xbf,
    bf16_t* __restrict__ wtq, bf16_t* __restrict__ wto) {
    __shared__ float t[32][33];
    const int bid = blockIdx.x;
    if (bid < 4096) {
        const int i = (bid * 256 + (int)threadIdx.x) * 4;
        const float4 v = *reinterpret_cast<const float4*>(query + i);
        bf16x4 o = { (bf16_t)v.x, (bf16_t)v.y, (bf16_t)v.z, (bf16_t)v.w };
        *reinterpret_cast<bf16x4*>(xbf + i) = o;
        return;
    }
    const int tx = threadIdx.x & 31, ty = threadIdx.x >> 5;  // 32 x 8
    if (bid < 10240) {
        const int u = bid - 4096;
        const int z = u >> 11, u2 = u & 2047;
        const int c0 = (u2 & 63) * 32, r0 = (u2 >> 6) * 32;   // C=2048, R=1024
        const float* in = (z == 0) ? Wq : (z == 1 ? Wk : Wv);
        bf16_t* o = wtq + (size_t)z * 2097152;
#pragma unroll
        for (int i = 0; i < 4; i++) t[ty + i * 8][tx] = in[(size_t)(r0 + ty + i * 8) * 2048 + c0 + tx];
        __syncthreads();
#pragma unroll
        for (int i = 0; i < 4; i++)
            o[(size_t)(c0 + ty + i * 8) * 1024 + r0 + tx] = (bf16_t)t[tx][ty + i * 8];
    } else {
        const int u = bid - 10240;
        const int c0 = (u & 31) * 32, r0 = (u >> 5) * 32;     // C=1024, R=2048
#pragma unroll
        for (int i = 0; i < 4; i++) t[ty + i * 8][tx] = Wo[(size_t)(r0 + ty + i * 8) * 1024 + c0 + tx];
        __syncthreads();
#pragma unroll
        for (int i = 0; i < 4; i++)
            wto[(size_t)(c0 + ty + i * 8) * 2048 + r0 + tx] = (bf16_t)t[tx][ty + i * 8];
    }
}

// ---------------- 128x128-tile bf16 GEMM, double-buffered (R12, verified) ----------------
template <int K, int N, bool OUTBF16, bool QKV>
__global__ __launch_bounds__(256) void gemm128(
    const bf16_t* __restrict__ A, const bf16_t* __restrict__ Bt,
    const float* __restrict__ b0, const float* __restrict__ b1, const float* __restrict__ b2,
    bf16_t* __restrict__ Cqk, bf16_t* __restrict__ Vt, float* __restrict__ Cf) {
    constexpr int NKT = K / 64;
    __shared__ __align__(16) char LS[65536];   // buf d: A @ d*32768, B @ d*32768+16384
    const int z = blockIdx.z;
    const bf16_t* Bz = Bt + (size_t)z * N * K;
    const float* bias = (z == 0) ? b0 : (z == 1 ? b1 : b2);
    const int m0 = blockIdx.y * 128, n0 = blockIdx.x * 128;
    const int tid = threadIdx.x, lane = tid & 63, wave = tid >> 6;
    const int wm = (wave >> 1) * 64, wn = (wave & 1) * 64;
    const int fr = lane & 15, fq = lane >> 4;

    f32x4 acc[4][4];
    const f32x4 fz = {0.f, 0.f, 0.f, 0.f};
#pragma unroll
    for (int i = 0; i < 4; i++)
#pragma unroll
        for (int j = 0; j < 4; j++) acc[i][j] = fz;

    auto stage = [&](int d, int kt) {
        const int k0 = kt * 64;
#pragma unroll
        for (int j = 0; j < 4; j++) {
            int cid = tid + 256 * j;
            int r = cid >> 3;
            int sc = ((cid & 7) ^ (r & 7)) << 3;
            gload16(A + (size_t)(m0 + r) * K + k0 + sc, LS + d * 32768 + cid * 16);
            gload16(Bz + (size_t)(n0 + r) * K + k0 + sc, LS + d * 32768 + 16384 + cid * 16);
        }
    };

    stage(0, 0);
    asm volatile("s_waitcnt vmcnt(0)" ::: "memory");
    __builtin_amdgcn_s_barrier();
    __builtin_amdgcn_sched_barrier(0);

    for (int kt = 0; kt < NKT; ++kt) {
        if (kt + 1 < NKT) stage((kt + 1) & 1, kt + 1);
        const char* Ab = LS + (kt & 1) * 32768;
        const char* Bb = Ab + 16384;
#pragma unroll
        for (int ks = 0; ks < 2; ++ks) {
            bf16x8 af[4], bfv[4];
#pragma unroll
            for (int mi = 0; mi < 4; mi++) {
                int r = wm + mi * 16 + fr;
                int cb = (ks * 64 + fq * 16) ^ ((r & 7) << 4);
                af[mi] = *reinterpret_cast<const bf16x8*>(Ab + r * 128 + cb);
            }
#pragma unroll
            for (int ni = 0; ni < 4; ni++) {
                int r = wn + ni * 16 + fr;
                int cb = (ks * 64 + fq * 16) ^ ((r & 7) << 4);
                bfv[ni] = *reinterpret_cast<const bf16x8*>(Bb + r * 128 + cb);
            }
            __builtin_amdgcn_s_setprio(1);
#pragma unroll
            for (int mi = 0; mi < 4; mi++)
#pragma unroll
                for (int ni = 0; ni < 4; ni++) acc[mi][ni] = mfma16(af[mi], bfv[ni], acc[mi][ni]);
            __builtin_amdgcn_s_setprio(0);
        }
        asm volatile("s_waitcnt vmcnt(0)" ::: "memory");
        __builtin_amdgcn_s_barrier();
        __builtin_amdgcn_sched_barrier(0);
    }

#pragma unroll
    for (int ni = 0; ni < 4; ni++) {
        const int col = n0 + wn + ni * 16 + fr;
        const float bb = bias[col];
#pragma unroll
        for (int mi = 0; mi < 4; mi++) {
            const int mrow = m0 + wm + mi * 16 + fq * 4;
            f32x4 v = acc[mi][ni];
            if (OUTBF16) {
                if (QKV && z == 2) {
                    const int b = mrow >> 11, s = mrow & (S_ - 1);
                    const int h = col >> 7, d = col & (DH - 1);
                    bf16x4 w = { (bf16_t)(v[0] + bb), (bf16_t)(v[1] + bb),
                                 (bf16_t)(v[2] + bb), (bf16_t)(v[3] + bb) };
                    *reinterpret_cast<bf16x4*>(Vt + ((size_t)((b * H_ + h) * DH + d)) * S_ + s) = w;
                } else {
                    bf16_t* Cz = Cqk + (size_t)z * M_ * N;
#pragma unroll
                    for (int j = 0; j < 4; j++)
                        Cz[(size_t)(mrow + j) * N + col] = (bf16_t)(v[j] + bb);
                }
            } else {
#pragma unroll
                for (int j = 0; j < 4; j++) Cf[(size_t)(mrow + j) * N + col] = v[j] + bb;
            }
        }
    }
}

// ---------------- causal flash attention, v11b ----------------
// v11b = R15's v11 structure (4 q-waves x 3 kv-streams, KVBLK=32, 768 threads) with
// the REAL fix: __launch_bounds__(768, 3). R15's bare (768) let the compiler target
// 6 waves/EU -> VGPR squeezed to 84 < ~112 live set -> spill storm (FETCH 24.6->37.4MB).
// The (.,3) arg caps occupancy target at 3 waves/EU -> VGPR budget ~170 -> no spill,
// true 3 concurrent chains/SIMD (the only lever that ever moved attn: R6, 1->2 waves).
constexpr int KTS = 8192;  // one 32x128 bf16 tile (K or V) in LDS

__global__ __launch_bounds__(768, 3) void attn(
    const bf16_t* __restrict__ Q, const bf16_t* __restrict__ Kc,
    const bf16_t* __restrict__ Vt, bf16_t* __restrict__ Ctx) {
    const int id = blockIdx.x;
    const int bh = id & 31, b = bh >> 4, h = bh & 15;
    const int pr = id >> 5;
    const int lane = threadIdx.x & 63, wave = threadIdx.x >> 6;   // 0..11
    const int fr = lane & 15, fq = lane >> 4;
    const int qw = wave & 3, strm = wave >> 2;                    // 4 q-waves x 3 streams

    __shared__ __align__(16) char L[98304];
    // K buf (st,p) @ (st*2+p)*KTS in [0,49152); V @ 49152 + (st*2+p)*KTS
    // merge slots (phase end, KV region dead): slot(qw) = L + qw*17408

    const bf16_t* Kbase = Kc + (size_t)b * S_ * AF + h * DH;
    const bf16_t* Vbase = Vt + (size_t)bh * DH * S_;
    const float scale2 = 0.0318793617f;  // 1/sqrt(2048) * log2(e)
    const f32x4 fz = {0.f, 0.f, 0.f, 0.f};

    auto stage = [&](int p, int t0) {
#pragma unroll
        for (int i = 0; i < 2; ++i) {
            const int c = (int)threadIdx.x + 768 * i;   // 0..1535
            const int st = c >> 9, ci = c & 511;
            int tt = t0 + st; tt = (tt > 63) ? 63 : tt;  // clamp: no OOB staging
            const int r = ci >> 4, cc = ci & 15;         // K row, 16B chunk in 256B row
            gload16(Kbase + (size_t)(tt * 32 + r) * AF + ((cc ^ (r & 7)) << 3),
                    L + (st * 2 + p) * KTS + ci * 16);
            const int rv = ci >> 2, cv = ci & 3;         // V row, 16B chunk in 64B row
            gload16(Vbase + (size_t)rv * S_ + tt * 32 + ((cv ^ (rv & 3)) << 3),
                    L + 49152 + (st * 2 + p) * KTS + ci * 16);
        }
    };

    for (int ph = 0; ph < 2; ++ph) {
        const int qt = ph ? (15 - pr) : pr;
        const int q0 = qt * 128;
        const int NT = 4 * qt + 4;          // tiles of 32 kv
        const int nst = (NT + 2) / 3;       // steps of 3 tiles

        bf16x8 qf[2][4];
#pragma unroll
        for (int qg = 0; qg < 2; ++qg) {
            const bf16_t* qp = Q + (size_t)(b * S_ + q0 + qw * 32 + qg * 16 + fr) * AF + h * DH + fq * 8;
#pragma unroll
            for (int ds = 0; ds < 4; ++ds) qf[qg][ds] = *reinterpret_cast<const bf16x8*>(qp + ds * 32);
        }
        float m_[2] = {-126.f, -126.f}, l_[2] = {0.f, 0.f};  // log2 domain; l per-lane partial
        f32x4 o[2][8];   // o[qg][df][r] = O[d = df*16+fq*4+r][q = own row fr]
#pragma unroll
        for (int qg = 0; qg < 2; ++qg)
#pragma unroll
            for (int d = 0; d < 8; ++d) o[qg][d] = fz;

        __syncthreads();           // L free (prev phase merge done)
        stage(0, 0);
        __syncthreads();           // step-0 tiles ready

        for (int k = 0; k < nst; ++k) {
            if (k + 1 < nst) stage((k + 1) & 1, 3 * (k + 1));
            const int ts = 3 * k + strm;
            if (ts < NT) {         // wave-uniform guard (idle streams skip to barrier)
                const int kv0 = ts * 32;
                const char* kb = L + (strm * 2 + (k & 1)) * KTS;
                const char* vb = L + 49152 + (strm * 2 + (k & 1)) * KTS;

                // ---- QK^T (swapped): sv[qg][kvf][r] = S[kv=kvf*16+fq*4+r][q=fr] ----
                f32x4 sv[2][2];
                __builtin_amdgcn_s_setprio(1);
#pragma unroll
                for (int kvf = 0; kvf < 2; ++kvf) {
                    bf16x8 kf[4];
#pragma unroll
                    for (int ds = 0; ds < 4; ++ds) {
                        const int r = kvf * 16 + fr;
                        kf[ds] = *reinterpret_cast<const bf16x8*>(kb + r * 256 + ((ds * 64 + fq * 16) ^ ((r & 7) << 4)));
                    }
                    sv[0][kvf] = fz; sv[1][kvf] = fz;
#pragma unroll
                    for (int ds = 0; ds < 4; ++ds) {
                        sv[0][kvf] = mfma16(kf[ds], qf[0][ds], sv[0][kvf]);
                        sv[1][kvf] = mfma16(kf[ds], qf[1][ds], sv[1][kvf]);
                    }
                }
                __builtin_amdgcn_s_setprio(0);
                const bool diag = (ts >= 4 * qt);

                // ---- softmax per qg (log2); P packed to bf16 pairs in registers ----
                uint32_t pk[2][4];
#pragma unroll
                for (int qg = 0; qg < 2; ++qg) {
                    const int q_abs = q0 + qw * 32 + qg * 16 + fr;
                    float x[8], mx = -3.0e38f;
#pragma unroll
                    for (int kvf = 0; kvf < 2; ++kvf)
#pragma unroll
                        for (int r = 0; r < 4; ++r) {
                            float tv = sv[qg][kvf][r] * scale2;
                            if (diag && (kv0 + kvf * 16 + fq * 4 + r > q_abs)) tv = -3.0e38f;
                            x[kvf * 4 + r] = tv;
                            mx = fmaxf(mx, tv);
                        }
                    mx = fmaxf(mx, __shfl_xor(mx, 16, 64));
                    mx = fmaxf(mx, __shfl_xor(mx, 32, 64));
                    float mnew = m_[qg];
                    if (!__all(mx <= m_[qg] + 11.54f)) {   // defer-max (T13)
                        mnew = fmaxf(m_[qg], mx);
                        const float corr = exp2v(m_[qg] - mnew);
                        l_[qg] *= corr;
#pragma unroll
                        for (int d = 0; d < 8; ++d)
#pragma unroll
                            for (int r = 0; r < 4; ++r) o[qg][d][r] *= corr;
                        m_[qg] = mnew;
                    }
                    float rs = 0.f;
#pragma unroll
                    for (int jj = 0; jj < 8; ++jj) { x[jj] = exp2v(x[jj] - mnew); rs += x[jj]; }
                    l_[qg] += rs;          // per-lane partial; reduce deferred to phase end
#pragma unroll
                    for (int j = 0; j < 4; ++j)
                        asm("v_cvt_pk_bf16_f32 %0, %1, %2" : "=v"(pk[qg][j]) : "v"(x[2 * j]), "v"(x[2 * j + 1]));
                }

                // ---- swapped PV (KVBLK=32): o[qg][df] = mfma(V-rows, P-rows) ----
                // dest lane (fr,fq), word w: src lane ((fq&1)*2+(w>>1))*16+fr (uniform),
                // src word (fq>>1)*2+(w&1) -> shfl BOTH, select on fq>>1 (R9 lesson)
                {
                    const int sl0 = ((fq & 1) * 2) * 16 + fr;
                    bf16x8 pb[2];
#pragma unroll
                    for (int qg = 0; qg < 2; ++qg) {
                        union { uint32_t w[4]; bf16x8 v; } u;
#pragma unroll
                        for (int w = 0; w < 4; ++w) {
                            const int sl = sl0 + (w >> 1) * 16;
                            const int a0 = __shfl((int)pk[qg][(w & 1)], sl, 64);
                            const int a1 = __shfl((int)pk[qg][2 + (w & 1)], sl, 64);
                            u.w[w] = (uint32_t)((fq >> 1) ? a1 : a0);
                        }
                        pb[qg] = u.v;
                    }
                    __builtin_amdgcn_s_setprio(1);
#pragma unroll
                    for (int df = 0; df < 8; ++df) {
                        const int rv = df * 16 + fr;
                        const bf16x8 av = *reinterpret_cast<const bf16x8*>(
                            vb + rv * 64 + ((fq * 16) ^ ((rv & 3) << 4)));
                        o[0][df] = mfma16(av, pb[0], o[0][df]);
                        o[1][df] = mfma16(av, pb[1], o[1][df]);
                    }
                    __builtin_amdgcn_s_setprio(0);
                }
            }
            __syncthreads();  // next step staged & current reads done
        }

        // ---- deferred l-reduce, then sequential 2-round merge (slot reuse) ----
#pragma unroll
        for (int qg = 0; qg < 2; ++qg) {
            l_[qg] += __shfl_xor(l_[qg], 16, 64);
            l_[qg] += __shfl_xor(l_[qg], 32, 64);
        }
        char* const sp = L + qw * 17408;   // o 16384 B + ml 1024 B
        if (strm == 1) {
#pragma unroll
            for (int qg = 0; qg < 2; ++qg) {
#pragma unroll
                for (int df = 0; df < 8; ++df)
                    *reinterpret_cast<f32x4*>(sp + (qg * 8 + df) * 1024 + lane * 16) = o[qg][df];
                float2 ml = { m_[qg], l_[qg] };
                *reinterpret_cast<float2*>(sp + 16384 + (qg * 64 + lane) * 8) = ml;
            }
        }
        __syncthreads();
        if (strm == 0) {
#pragma unroll
            for (int qg = 0; qg < 2; ++qg) {
                const float2 ml = *reinterpret_cast<const float2*>(sp + 16384 + (qg * 64 + lane) * 8);
                const float mm = fmaxf(m_[qg], ml.x);
                const float c0 = exp2v(m_[qg] - mm), c1 = exp2v(ml.x - mm);
                m_[qg] = mm;
                l_[qg] = l_[qg] * c0 + ml.y * c1;
#pragma unroll
                for (int df = 0; df < 8; ++df) {
                    const f32x4 o1 = *reinterpret_cast<const f32x4*>(sp + (qg * 8 + df) * 1024 + lane * 16);
#pragma unroll
                    for (int r = 0; r < 4; ++r) o[qg][df][r] = o[qg][df][r] * c0 + o1[r] * c1;
                }
            }
        }
        __syncthreads();
        if (strm == 2) {
#pragma unroll
            for (int qg = 0; qg < 2; ++qg) {
#pragma unroll
                for (int df = 0; df < 8; ++df)
                    *reinterpret_cast<f32x4*>(sp + (qg * 8 + df) * 1024 + lane * 16) = o[qg][df];
                float2 ml = { m_[qg], l_[qg] };
                *reinterpret_cast<float2*>(sp + 16384 + (qg * 64 + lane) * 8) = ml;
            }
        }
        __syncthreads();
        if (strm == 0) {
#pragma unroll
            for (int qg = 0; qg < 2; ++qg) {
                const float2 ml = *reinterpret_cast<const float2*>(sp + 16384 + (qg * 64 + lane) * 8);
                const float mm = fmaxf(m_[qg], ml.x);
                const float c0 = exp2v(m_[qg] - mm), c1 = exp2v(ml.x - mm);
                const float li = 1.0f / (l_[qg] * c0 + ml.y * c1);
                const size_t row = (size_t)(b * S_ + q0 + qw * 32 + qg * 16 + fr);
#pragma unroll
                for (int df = 0; df < 8; ++df) {
                    const f32x4 o1 = *reinterpret_cast<const f32x4*>(sp + (qg * 8 + df) * 1024 + lane * 16);
                    bf16x4 w;
#pragma unroll
                    for (int r = 0; r < 4; ++r)
                        w[r] = (bf16_t)((o[qg][df][r] * c0 + o1[r] * c1) * li);
                    *reinterpret_cast<bf16x4*>(Ctx + row * AF + h * DH + df * 16 + fq * 4) = w;
                }
            }
        }
        __syncthreads();  // KV/merge region free before next phase staging
    }
}

extern "C" void kernel_launch(void* const* d_in, const int* in_sizes, int n_in,
                              void* d_out, int out_size, void* d_ws, size_t ws_size,
                              hipStream_t stream) {
    const float* query = (const float*)d_in[0];
    const float* Wq = (const float*)d_in[1];
    const float* bq = (const float*)d_in[2];
    const float* Wk = (const float*)d_in[3];
    const float* bk = (const float*)d_in[4];
    const float* Wv = (const float*)d_in[5];
    const float* bv = (const float*)d_in[6];
    const float* Wo = (const float*)d_in[7];
    const float* bo = (const float*)d_in[8];
    float* out = (float*)d_out;
    char* ws = (char*)d_ws;

    bf16_t* xbf  = (bf16_t*)(ws + 0);
    bf16_t* wtq  = (bf16_t*)(ws + 8388608);
    bf16_t* wto  = (bf16_t*)(ws + 20971520);
    bf16_t* qws  = (bf16_t*)(ws + 25165824);
    bf16_t* vtws = (bf16_t*)(ws + 58720256);
    bf16_t* ctx  = (bf16_t*)(ws + 0);

    prep<<<12288, 256, 0, stream>>>(query, Wq, Wk, Wv, Wo, xbf, wtq, wto);

    gemm128<1024, 2048, true, true><<<dim3(16, 32, 3), 256, 0, stream>>>(
        xbf, wtq, bq, bk, bv, qws, vtws, nullptr);

    attn<<<512, 768, 0, stream>>>(qws, qws + (size_t)4096 * 2048, vtws, ctx);

    gemm128<2048, 1024, false, false><<<dim3(8, 32, 1), 256, 0, stream>>>(
        ctx, wto, bo, bo, bo, nullptr, nullptr, out);
}

// Round 18
// 164.595 us; speedup vs baseline: 1.4417x; 1.4417x over previous
//
#include <hip/hip_runtime.h>

typedef __bf16 bf16_t;
typedef __bf16 bf16x8 __attribute__((ext_vector_type(8)));
typedef __bf16 bf16x4 __attribute__((ext_vector_type(4)));
typedef float f32x4 __attribute__((ext_vector_type(4)));

static __device__ __forceinline__ f32x4 mfma16(bf16x8 a, bf16x8 b, f32x4 c) {
    return __builtin_amdgcn_mfma_f32_16x16x32_bf16(a, b, c, 0, 0, 0);
}
static __device__ __forceinline__ float exp2v(float x) {
    float r; asm("v_exp_f32 %0, %1" : "=v"(r) : "v"(x)); return r;
}

#define AS1 __attribute__((address_space(1)))
#define AS3 __attribute__((address_space(3)))
static __device__ __forceinline__ void gload16(const void* g, void* l) {
    __builtin_amdgcn_global_load_lds((AS1 const void*)g, (AS3 void*)l, 16, 0, 0);
}

constexpr int B_ = 2, S_ = 2048, H_ = 16, DH = 128, AF = 2048;
constexpr int M_ = B_ * S_;  // 4096

// ---------------- fused prep: query cvt + Wq/Wk/Wv transpose + Wo transpose ----------------
__global__ __launch_bounds__(256) void prep(
    const float* __restrict__ query, const float* __restrict__ Wq,
    const float* __restrict__ Wk, const float* __restrict__ Wv,
    const float* __restrict__ Wo, bf16_t* __restrict__ xbf,
    bf16_t* __restrict__ wtq, bf16_t* __restrict__ wto) {
    __shared__ float t[32][33];
    const int bid = blockIdx.x;
    if (bid < 4096) {
        const int i = (bid * 256 + (int)threadIdx.x) * 4;
        const float4 v = *reinterpret_cast<const float4*>(query + i);
        bf16x4 o = { (bf16_t)v.x, (bf16_t)v.y, (bf16_t)v.z, (bf16_t)v.w };
        *reinterpret_cast<bf16x4*>(xbf + i) = o;
        return;
    }
    const int tx = threadIdx.x & 31, ty = threadIdx.x >> 5;  // 32 x 8
    if (bid < 10240) {
        const int u = bid - 4096;
        const int z = u >> 11, u2 = u & 2047;
        const int c0 = (u2 & 63) * 32, r0 = (u2 >> 6) * 32;   // C=2048, R=1024
        const float* in = (z == 0) ? Wq : (z == 1 ? Wk : Wv);
        bf16_t* o = wtq + (size_t)z * 2097152;
#pragma unroll
        for (int i = 0; i < 4; i++) t[ty + i * 8][tx] = in[(size_t)(r0 + ty + i * 8) * 2048 + c0 + tx];
        __syncthreads();
#pragma unroll
        for (int i = 0; i < 4; i++)
            o[(size_t)(c0 + ty + i * 8) * 1024 + r0 + tx] = (bf16_t)t[tx][ty + i * 8];
    } else {
        const int u = bid - 10240;
        const int c0 = (u & 31) * 32, r0 = (u >> 5) * 32;     // C=1024, R=2048
#pragma unroll
        for (int i = 0; i < 4; i++) t[ty + i * 8][tx] = Wo[(size_t)(r0 + ty + i * 8) * 1024 + c0 + tx];
        __syncthreads();
#pragma unroll
        for (int i = 0; i < 4; i++)
            wto[(size_t)(c0 + ty + i * 8) * 2048 + r0 + tx] = (bf16_t)t[tx][ty + i * 8];
    }
}

// ---------------- 128x128-tile bf16 GEMM, double-buffered (R12, verified) ----------------
template <int K, int N, bool OUTBF16, bool QKV>
__global__ __launch_bounds__(256) void gemm128(
    const bf16_t* __restrict__ A, const bf16_t* __restrict__ Bt,
    const float* __restrict__ b0, const float* __restrict__ b1, const float* __restrict__ b2,
    bf16_t* __restrict__ Cqk, bf16_t* __restrict__ Vt, float* __restrict__ Cf) {
    constexpr int NKT = K / 64;
    __shared__ __align__(16) char LS[65536];   // buf d: A @ d*32768, B @ d*32768+16384
    const int z = blockIdx.z;
    const bf16_t* Bz = Bt + (size_t)z * N * K;
    const float* bias = (z == 0) ? b0 : (z == 1 ? b1 : b2);
    const int m0 = blockIdx.y * 128, n0 = blockIdx.x * 128;
    const int tid = threadIdx.x, lane = tid & 63, wave = tid >> 6;
    const int wm = (wave >> 1) * 64, wn = (wave & 1) * 64;
    const int fr = lane & 15, fq = lane >> 4;

    f32x4 acc[4][4];
    const f32x4 fz = {0.f, 0.f, 0.f, 0.f};
#pragma unroll
    for (int i = 0; i < 4; i++)
#pragma unroll
        for (int j = 0; j < 4; j++) acc[i][j] = fz;

    auto stage = [&](int d, int kt) {
        const int k0 = kt * 64;
#pragma unroll
        for (int j = 0; j < 4; j++) {
            int cid = tid + 256 * j;
            int r = cid >> 3;
            int sc = ((cid & 7) ^ (r & 7)) << 3;
            gload16(A + (size_t)(m0 + r) * K + k0 + sc, LS + d * 32768 + cid * 16);
            gload16(Bz + (size_t)(n0 + r) * K + k0 + sc, LS + d * 32768 + 16384 + cid * 16);
        }
    };

    stage(0, 0);
    asm volatile("s_waitcnt vmcnt(0)" ::: "memory");
    __builtin_amdgcn_s_barrier();
    __builtin_amdgcn_sched_barrier(0);

    for (int kt = 0; kt < NKT; ++kt) {
        if (kt + 1 < NKT) stage((kt + 1) & 1, kt + 1);
        const char* Ab = LS + (kt & 1) * 32768;
        const char* Bb = Ab + 16384;
#pragma unroll
        for (int ks = 0; ks < 2; ++ks) {
            bf16x8 af[4], bfv[4];
#pragma unroll
            for (int mi = 0; mi < 4; mi++) {
                int r = wm + mi * 16 + fr;
                int cb = (ks * 64 + fq * 16) ^ ((r & 7) << 4);
                af[mi] = *reinterpret_cast<const bf16x8*>(Ab + r * 128 + cb);
            }
#pragma unroll
            for (int ni = 0; ni < 4; ni++) {
                int r = wn + ni * 16 + fr;
                int cb = (ks * 64 + fq * 16) ^ ((r & 7) << 4);
                bfv[ni] = *reinterpret_cast<const bf16x8*>(Bb + r * 128 + cb);
            }
            __builtin_amdgcn_s_setprio(1);
#pragma unroll
            for (int mi = 0; mi < 4; mi++)
#pragma unroll
                for (int ni = 0; ni < 4; ni++) acc[mi][ni] = mfma16(af[mi], bfv[ni], acc[mi][ni]);
            __builtin_amdgcn_s_setprio(0);
        }
        asm volatile("s_waitcnt vmcnt(0)" ::: "memory");
        __builtin_amdgcn_s_barrier();
        __builtin_amdgcn_sched_barrier(0);
    }

#pragma unroll
    for (int ni = 0; ni < 4; ni++) {
        const int col = n0 + wn + ni * 16 + fr;
        const float bb = bias[col];
#pragma unroll
        for (int mi = 0; mi < 4; mi++) {
            const int mrow = m0 + wm + mi * 16 + fq * 4;
            f32x4 v = acc[mi][ni];
            if (OUTBF16) {
                if (QKV && z == 2) {
                    const int b = mrow >> 11, s = mrow & (S_ - 1);
                    const int h = col >> 7, d = col & (DH - 1);
                    bf16x4 w = { (bf16_t)(v[0] + bb), (bf16_t)(v[1] + bb),
                                 (bf16_t)(v[2] + bb), (bf16_t)(v[3] + bb) };
                    *reinterpret_cast<bf16x4*>(Vt + ((size_t)((b * H_ + h) * DH + d)) * S_ + s) = w;
                } else {
                    bf16_t* Cz = Cqk + (size_t)z * M_ * N;
#pragma unroll
                    for (int j = 0; j < 4; j++)
                        Cz[(size_t)(mrow + j) * N + col] = (bf16_t)(v[j] + bb);
                }
            } else {
#pragma unroll
                for (int j = 0; j < 4; j++) Cf[(size_t)(mrow + j) * N + col] = v[j] + bb;
            }
        }
    }
}

// ---------------- causal flash attention, v10 (R14/R16, best verified) ----------------
constexpr int TS_ = 16384;  // one 64x128 bf16 tile in LDS

__global__ __launch_bounds__(512, 2) void attn(
    const bf16_t* __restrict__ Q, const bf16_t* __restrict__ Kc,
    const bf16_t* __restrict__ Vt, bf16_t* __restrict__ Ctx) {
    const int id = blockIdx.x;
    const int bh = id & 31, b = bh >> 4, h = bh & 15;
    const int pr = id >> 5;
    const int lane = threadIdx.x & 63, wave = threadIdx.x >> 6;
    const int fr = lane & 15, fq = lane >> 4;
    const int qw = wave & 3, strm = wave >> 2;

    __shared__ __align__(16) char L[131072];  // K bufs [s][p] @ (s*2+p)*TS_, V @ 65536+...

    const bf16_t* Kbase = Kc + (size_t)b * S_ * AF + h * DH;
    const bf16_t* Vbase = Vt + (size_t)bh * DH * S_;
    const float scale2 = 0.0318793617f;  // 1/sqrt(2048) * log2(e)
    const f32x4 fz = {0.f, 0.f, 0.f, 0.f};

    auto stage = [&](int p, int t0) {
#pragma unroll
        for (int i = 0; i < 2; ++i) {
            const int c = (int)threadIdx.x + 512 * i;
            const int r = c >> 4, cc = c & 15;
            gload16(Kbase + (size_t)(t0 * 64 + r) * AF + ((cc ^ (r & 7)) << 3),
                    L + (0 * 2 + p) * TS_ + c * 16);
            gload16(Kbase + (size_t)((t0 + 1) * 64 + r) * AF + ((cc ^ (r & 7)) << 3),
                    L + (1 * 2 + p) * TS_ + c * 16);
            const int rv = c >> 3, cv = c & 7;
            gload16(Vbase + (size_t)rv * S_ + t0 * 64 + ((cv ^ (rv & 7)) << 3),
                    L + 65536 + (0 * 2 + p) * TS_ + c * 16);
            gload16(Vbase + (size_t)rv * S_ + (t0 + 1) * 64 + ((cv ^ (rv & 7)) << 3),
                    L + 65536 + (1 * 2 + p) * TS_ + c * 16);
        }
    };

    for (int ph = 0; ph < 2; ++ph) {
        const int qt = ph ? (15 - pr) : pr;
        const int q0 = qt * 128;
        const int nst = qt + 1;

        bf16x8 qf[2][4];
#pragma unroll
        for (int qg = 0; qg < 2; ++qg) {
            const bf16_t* qp = Q + (size_t)(b * S_ + q0 + qw * 32 + qg * 16 + fr) * AF + h * DH + fq * 8;
#pragma unroll
            for (int ds = 0; ds < 4; ++ds) qf[qg][ds] = *reinterpret_cast<const bf16x8*>(qp + ds * 32);
        }
        float m_[2] = {-126.f, -126.f}, l_[2] = {0.f, 0.f};  // log2 domain; l_ = per-lane partial
        f32x4 o[2][8];   // o[qg][df][r] = O[d = df*16+fq*4+r][q = own row fr]
#pragma unroll
        for (int qg = 0; qg < 2; ++qg)
#pragma unroll
            for (int d = 0; d < 8; ++d) o[qg][d] = fz;

        __syncthreads();
        stage(0, 0);
        __syncthreads();

        for (int k = 0; k < nst; ++k) {
            if (k + 1 < nst) stage((k + 1) & 1, 2 * k + 2);
            const int ts = 2 * k + strm;
            const int kv0 = ts * 64;
            const char* kb = L + (strm * 2 + (k & 1)) * TS_;
            const char* vb = L + 65536 + (strm * 2 + (k & 1)) * TS_;

            // ---- QK^T fused for both qg (kf reads shared) ----
            f32x4 sv[2][4];
            __builtin_amdgcn_s_setprio(1);
#pragma unroll
            for (int kvf = 0; kvf < 4; ++kvf) {
                bf16x8 kf[4];
#pragma unroll
                for (int ds = 0; ds < 4; ++ds) {
                    const int r = kvf * 16 + fr;
                    kf[ds] = *reinterpret_cast<const bf16x8*>(kb + r * 256 + ((ds * 64 + fq * 16) ^ ((r & 7) << 4)));
                }
                sv[0][kvf] = fz; sv[1][kvf] = fz;
#pragma unroll
                for (int ds = 0; ds < 4; ++ds) {
                    sv[0][kvf] = mfma16(kf[ds], qf[0][ds], sv[0][kvf]);
                    sv[1][kvf] = mfma16(kf[ds], qf[1][ds], sv[1][kvf]);
                }
            }
            __builtin_amdgcn_s_setprio(0);
            const bool diag = (ts >= 2 * qt);

            // ---- softmax per qg (log2 domain); P packed to bf16 pairs in registers ----
            uint32_t pk[2][8];
#pragma unroll
            for (int qg = 0; qg < 2; ++qg) {
                const int q_abs = q0 + qw * 32 + qg * 16 + fr;
                float x[16], mx = -3.0e38f;
#pragma unroll
                for (int kvf = 0; kvf < 4; ++kvf)
#pragma unroll
                    for (int r = 0; r < 4; ++r) {
                        float tv = sv[qg][kvf][r] * scale2;
                        if (diag && (kv0 + kvf * 16 + fq * 4 + r > q_abs)) tv = -3.0e38f;
                        x[kvf * 4 + r] = tv;
                        mx = fmaxf(mx, tv);
                    }
                mx = fmaxf(mx, __shfl_xor(mx, 16, 64));
                mx = fmaxf(mx, __shfl_xor(mx, 32, 64));
                float mnew = m_[qg];
                if (!__all(mx <= m_[qg] + 11.54f)) {   // defer-max (T13), log2 units
                    mnew = fmaxf(m_[qg], mx);
                    const float corr = exp2v(m_[qg] - mnew);   // lane-local
                    l_[qg] *= corr;
#pragma unroll
                    for (int d = 0; d < 8; ++d)
#pragma unroll
                        for (int r = 0; r < 4; ++r) o[qg][d][r] *= corr;
                    m_[qg] = mnew;
                }
                float rs = 0.f;
#pragma unroll
                for (int jj = 0; jj < 16; ++jj) { x[jj] = exp2v(x[jj] - mnew); rs += x[jj]; }
                l_[qg] += rs;              // per-lane partial; cross-fq reduce deferred
#pragma unroll
                for (int j = 0; j < 8; ++j)
                    asm("v_cvt_pk_bf16_f32 %0, %1, %2" : "=v"(pk[qg][j]) : "v"(x[2 * j]), "v"(x[2 * j + 1]));
            }

            // ---- swapped PV with SHARED av reads: o[qg][df] = mfma(V-rows, P-rows) ----
#pragma unroll
            for (int ks = 0; ks < 2; ++ks) {
                const int sl0 = ((fq & 1) * 2) * 16 + fr;
                bf16x8 pb[2];
#pragma unroll
                for (int qg = 0; qg < 2; ++qg) {
                    union { uint32_t w[4]; bf16x8 v; } u;
#pragma unroll
                    for (int w = 0; w < 4; ++w) {
                        const int sl = sl0 + (w >> 1) * 16;
                        const int a0 = __shfl((int)pk[qg][ks * 4 + (w & 1)], sl, 64);
                        const int a1 = __shfl((int)pk[qg][ks * 4 + 2 + (w & 1)], sl, 64);
                        u.w[w] = (uint32_t)((fq >> 1) ? a1 : a0);
                    }
                    pb[qg] = u.v;
                }
                __builtin_amdgcn_s_setprio(1);
#pragma unroll
                for (int df = 0; df < 8; ++df) {
                    const int rv = df * 16 + fr;
                    const bf16x8 av = *reinterpret_cast<const bf16x8*>(
                        vb + rv * 128 + ((ks * 64 + fq * 16) ^ ((rv & 7) << 4)));
                    o[0][df] = mfma16(av, pb[0], o[0][df]);
                    o[1][df] = mfma16(av, pb[1], o[1][df]);
                }
                __builtin_amdgcn_s_setprio(0);
            }
            __syncthreads();
        }

        // ---- deferred l-reduce (once per phase), then stream merge + epilogue ----
#pragma unroll
        for (int qg = 0; qg < 2; ++qg) {
            l_[qg] += __shfl_xor(l_[qg], 16, 64);
            l_[qg] += __shfl_xor(l_[qg], 32, 64);
        }
        if (strm == 1) {
#pragma unroll
            for (int qg = 0; qg < 2; ++qg) {
#pragma unroll
                for (int df = 0; df < 8; ++df)
                    *reinterpret_cast<f32x4*>(L + qw * 16384 + (qg * 8 + df) * 1024 + lane * 16) = o[qg][df];
                float2 ml = { m_[qg], l_[qg] };
                *reinterpret_cast<float2*>(L + 65536 + ((qw * 2 + qg) * 64 + lane) * 8) = ml;
            }
        }
        __syncthreads();
        if (strm == 0) {
#pragma unroll
            for (int qg = 0; qg < 2; ++qg) {
                const float2 ml1 = *reinterpret_cast<const float2*>(
                    L + 65536 + ((qw * 2 + qg) * 64 + lane) * 8);
                const float mm = fmaxf(m_[qg], ml1.x);
                const float c0 = exp2v(m_[qg] - mm);
                const float c1 = exp2v(ml1.x - mm);
                const float li = 1.0f / (l_[qg] * c0 + ml1.y * c1);
                const size_t row = (size_t)(b * S_ + q0 + qw * 32 + qg * 16 + fr);
#pragma unroll
                for (int df = 0; df < 8; ++df) {
                    const f32x4 o1 = *reinterpret_cast<const f32x4*>(
                        L + qw * 16384 + (qg * 8 + df) * 1024 + lane * 16);
                    bf16x4 w;
#pragma unroll
                    for (int r = 0; r < 4; ++r)
                        w[r] = (bf16_t)((o[qg][df][r] * c0 + o1[r] * c1) * li);
                    *reinterpret_cast<bf16x4*>(Ctx + row * AF + h * DH + df * 16 + fq * 4) = w;
                }
            }
        }
        __syncthreads();
    }
}

extern "C" void kernel_launch(void* const* d_in, const int* in_sizes, int n_in,
                              void* d_out, int out_size, void* d_ws, size_t ws_size,
                              hipStream_t stream) {
    const float* query = (const float*)d_in[0];
    const float* Wq = (const float*)d_in[1];
    const float* bq = (const float*)d_in[2];
    const float* Wk = (const float*)d_in[3];
    const float* bk = (const float*)d_in[4];
    const float* Wv = (const float*)d_in[5];
    const float* bv = (const float*)d_in[6];
    const float* Wo = (const float*)d_in[7];
    const float* bo = (const float*)d_in[8];
    float* out = (float*)d_out;
    char* ws = (char*)d_ws;

    bf16_t* xbf  = (bf16_t*)(ws + 0);
    bf16_t* wtq  = (bf16_t*)(ws + 8388608);
    bf16_t* wto  = (bf16_t*)(ws + 20971520);
    bf16_t* qws  = (bf16_t*)(ws + 25165824);
    bf16_t* vtws = (bf16_t*)(ws + 58720256);
    bf16_t* ctx  = (bf16_t*)(ws + 0);

    prep<<<12288, 256, 0, stream>>>(query, Wq, Wk, Wv, Wo, xbf, wtq, wto);

    gemm128<1024, 2048, true, true><<<dim3(16, 32, 3), 256, 0, stream>>>(
        xbf, wtq, bq, bk, bv, qws, vtws, nullptr);

    attn<<<256, 512, 0, stream>>>(qws, qws + (size_t)4096 * 2048, vtws, ctx);

    gemm128<2048, 1024, false, false><<<dim3(8, 32, 1), 256, 0, stream>>>(
        ctx, wto, bo, bo, bo, nullptr, nullptr, out);
}